// Round 8
// baseline (780.183 us; speedup 1.0000x reference)
//
#include <hip/hip_runtime.h>
#include <stdint.h>

typedef __bf16 bf16;
typedef bf16 bf16x8 __attribute__((ext_vector_type(8)));
typedef float f32x4 __attribute__((ext_vector_type(4)));

#define GRID_H 512
#define GRID_W 512
#define FD 64
#define HD 256

// ---- ws layout (bytes) ----
#define WS_W1F 0          // 32768  : W1 frags, 32 blocks of 1KB, id = kt*16+mt (kt<2)
#define WS_W2F 32768      // 131072 : W2 frags, 128 blocks, id = kt*16+mt (kt<8)  [pi-permuted k]
#define WS_W3P 163840     // 4096   : 256 x float4 (w3 row padded)

// ---- LDS layout (bytes): weights only, staged once per persistent block ----
#define LDS_W1 0          // 32768
#define LDS_W2 32768      // 131072
#define LDS_TOTAL 163840  // exactly 160 KiB, STATIC so the compiler can see it

#define NBLOCKS 1024
#define PTS_PER_ITER 128  // 8 waves x 16 pts

#define FENCE() __builtin_amdgcn_sched_barrier(0)

__device__ __forceinline__ f32x4 mfma16(bf16x8 a, bf16x8 b, f32x4 c) {
  return __builtin_amdgcn_mfma_f32_16x16x32_bf16(a, b, c, 0, 0, 0);
}

// Fragment convention (A and B operands, consistent on both sides):
//   position (lane, j) <-> k = 32*kt + 8*(lane>>4) + j ; m/n = 16*mt + (lane&15)
// W2 ONLY: k-space is pi-permuted so that L1's D-fragments ARE L2's B-fragments
// in-lane:  channel stored at B-position (kt,g,j) = 32*kt + 16*(j>>2) + 4*g + (j&3).
// (R4-verified correct.)
__global__ __launch_bounds__(256) void nf_prep(
    const float* __restrict__ W1, const float* __restrict__ W2,
    const float* __restrict__ W3,
    bf16* __restrict__ w1f, bf16* __restrict__ w2f, float4* __restrict__ w3p)
{
  int t = blockIdx.x * 256 + threadIdx.x;
  if (t < 16384) {                       // W1^T frags: A[m=out][k=in] = W1[k][m]
    int e = t, blk = e >> 9, el = e & 511;
    int lane = el >> 3, j = el & 7;
    int kt = blk >> 4, mt = blk & 15;
    int k = kt * 32 + (lane >> 4) * 8 + j;   // in-ch < 64 (standard convention)
    int m = mt * 16 + (lane & 15);           // out-ch < 256
    w1f[e] = (bf16)W1[k * HD + m];
  } else if (t < 16384 + 65536) {        // W2^T frags with pi-permuted k
    int e = t - 16384, blk = e >> 9, el = e & 511;
    int lane = el >> 3, j = el & 7;
    int kt = blk >> 4, mt = blk & 15;
    int k = kt * 32 + ((j >> 2) << 4) + ((lane >> 4) << 2) + (j & 3);  // pi(k_pos)
    int m = mt * 16 + (lane & 15);           // out-ch < 256
    w2f[e] = (bf16)W2[k * HD + m];
  } else if (t < 16384 + 65536 + 256) {  // W3 rows padded to float4
    int c = t - 16384 - 65536;
    w3p[c] = make_float4(W3[c * 3 + 0], W3[c * 3 + 1], W3[c * 3 + 2], 0.f);
  }
}

// Persistent fused kernel: 1024 blocks x 512 threads (8 waves), 8 iters of
// 128 points.  Weights LDS-resident (160 KB, staged once); zero barriers in
// the main loop.
// vs R7: LDS is STATIC (compile-time 160 KB).  With dynamic LDS the compiler
// could not prove 1 WG/CU -> it budgeted 128 VGPR (4 waves/EU heuristic) and
// spilled h1b to scratch (R7: +1.6 GB FETCH / +400 MB WRITE, 4:1 = h1b
// re-read per L2 quarter).  Static LDS forces the occupancy calc to
// 2 waves/EU -> 256-VGPR budget -> no spills.  Fences kept from R7.
__global__ __launch_bounds__(512)
__attribute__((amdgpu_waves_per_eu(2, 2)))
void nf_fused(
    const float* __restrict__ coords, const float* __restrict__ grid,
    const float* __restrict__ b1, const float* __restrict__ b2,
    const float* __restrict__ b3,
    const bf16* __restrict__ wsf, const float4* __restrict__ w3p,
    float* __restrict__ out, int iters)
{
  __shared__ __align__(16) unsigned char lds[LDS_TOTAL];   // STATIC 160 KiB
  const int tid = threadIdx.x;
  const int w = tid >> 6;        // wave id: owns 16 points per iter
  const int l = tid & 63;
  const int g = l >> 4;          // lane group
  const int r15 = l & 15;

  // ---------- stage W1f+W2f (contiguous 160 KB in ws) into LDS, once ----------
  {
    const uint4* src = (const uint4*)wsf;
    uint4* dst = (uint4*)lds;
#pragma unroll 4
    for (int i = 0; i < 20; ++i) dst[i * 512 + tid] = src[i * 512 + tid];
  }
  __syncthreads();   // the only barrier in the kernel

  const unsigned char* ldsA = lds + (unsigned)(l * 16);

  for (int it = 0; it < iters; ++it) {
    const int p = blockIdx.x * (iters * PTS_PER_ITER) + it * PTS_PER_ITER +
                  w * 16 + r15;

    // ---------- bilinear gather -> feats B-frags in registers (R3/R4-verified) --
    // B-frag (lane l, j) <-> k(ch) = kt*32 + 8g + j ; n(pt) = r15
    bf16x8 bfr[2];
    {
      float2 cxy = *(const float2*)(coords + 2 * p);
      float px = (cxy.x * 0.5f + 0.5f) * (float)(GRID_W - 1);
      float py = (cxy.y * 0.5f + 0.5f) * (float)(GRID_H - 1);
      float fx = fminf(fmaxf(floorf(px), 0.f), (float)(GRID_W - 2));
      float fy = fminf(fmaxf(floorf(py), 0.f), (float)(GRID_H - 2));
      int x0 = (int)fx, y0 = (int)fy;
      float tx = px - fx, ty = py - fy;
      float w00 = (1.f - tx) * (1.f - ty);
      float w01 = tx * (1.f - ty);
      float w10 = (1.f - tx) * ty;
      float w11 = tx * ty;
      const float4* p00 = (const float4*)grid + (y0 * GRID_W + x0) * (FD / 4);
      const float4* p01 = p00 + (FD / 4);
      const float4* p10 = p00 + GRID_W * (FD / 4);
      const float4* p11 = p10 + (FD / 4);
#pragma unroll
      for (int kt = 0; kt < 2; ++kt) {
#pragma unroll
        for (int q = 0; q < 2; ++q) {
          int idx = kt * 8 + 2 * g + q;   // float4 index: ch = 4*idx
          float4 a = p00[idx], b = p01[idx], c = p10[idx], d = p11[idx];
          float f0 = a.x * w00 + b.x * w01 + c.x * w10 + d.x * w11;
          float f1 = a.y * w00 + b.y * w01 + c.y * w10 + d.y * w11;
          float f2 = a.z * w00 + b.z * w01 + c.z * w10 + d.z * w11;
          float f3 = a.w * w00 + b.w * w01 + c.w * w10 + d.w * w11;
          bfr[kt][q * 4 + 0] = (bf16)f0;
          bfr[kt][q * 4 + 1] = (bf16)f1;
          bfr[kt][q * 4 + 2] = (bf16)f2;
          bfr[kt][q * 4 + 3] = (bf16)f3;
        }
      }
    }
    FENCE();   // gather results settled; keep L1 loads out of this region

    // ---------- layer 1 + h1 epilogue, in four m-quarters (regs only) ----------
    // D mapping: pt(col) = r15, ch(row) = mt*16 + 4g + reg.
    // pi-permuted W2 expects B-position (kt,g,j) to hold ch = 32kt+16(j>>2)+4g+(j&3)
    //   -> h1b[mt>>1][(mt&1)*4+reg] = D(mt, reg).  Zero cross-lane movement.
    bf16x8 h1b[8];
#pragma unroll
    for (int q4 = 0; q4 < 4; ++q4) {
      f32x4 acc1[4];
#pragma unroll
      for (int m4 = 0; m4 < 4; ++m4) acc1[m4] = (f32x4){0.f, 0.f, 0.f, 0.f};
#pragma unroll
      for (int kt = 0; kt < 2; ++kt) {
#pragma unroll
        for (int m4 = 0; m4 < 4; ++m4) {
          bf16x8 af = *(const bf16x8*)(ldsA + LDS_W1 +
                                       (kt * 16 + q4 * 4 + m4) * 1024);
          acc1[m4] = mfma16(af, bfr[kt], acc1[m4]);
        }
        FENCE();   // <=4 af (32 VGPR) in flight per segment
      }
#pragma unroll
      for (int m4 = 0; m4 < 4; ++m4) {
        int mt = q4 * 4 + m4;
        float4 b1v = *(const float4*)(b1 + mt * 16 + 4 * g);
        int kt2 = mt >> 1, hh = mt & 1;
        h1b[kt2][hh * 4 + 0] = (bf16)fmaxf(acc1[m4][0] + b1v.x, 0.f);
        h1b[kt2][hh * 4 + 1] = (bf16)fmaxf(acc1[m4][1] + b1v.y, 0.f);
        h1b[kt2][hh * 4 + 2] = (bf16)fmaxf(acc1[m4][2] + b1v.z, 0.f);
        h1b[kt2][hh * 4 + 3] = (bf16)fmaxf(acc1[m4][3] + b1v.w, 0.f);
      }
      FENCE();   // quarter's h1 packed before next quarter's loads issue
    }

    // ---------- layer 2 + layer 3, in four m-quarters ----------
    float o0 = 0.f, o1 = 0.f, o2 = 0.f;
#pragma unroll
    for (int q4 = 0; q4 < 4; ++q4) {
      f32x4 acc2[4];
#pragma unroll
      for (int m4 = 0; m4 < 4; ++m4) acc2[m4] = (f32x4){0.f, 0.f, 0.f, 0.f};
#pragma unroll
      for (int kt = 0; kt < 8; ++kt) {
#pragma unroll
        for (int m4 = 0; m4 < 4; ++m4) {
          bf16x8 af = *(const bf16x8*)(ldsA + LDS_W2 +
                                       (kt * 16 + q4 * 4 + m4) * 1024);
          acc2[m4] = mfma16(af, h1b[kt], acc2[m4]);
        }
        FENCE();   // <=4 af (32 VGPR) in flight per kt segment
      }
      // L3 partials for this quarter (fp32, registers)
#pragma unroll
      for (int m4 = 0; m4 < 4; ++m4) {
        int mt = q4 * 4 + m4;
        float4 b2v = *(const float4*)(b2 + mt * 16 + 4 * g);
        float4 w3a = w3p[mt * 16 + 4 * g + 0];
        float4 w3b = w3p[mt * 16 + 4 * g + 1];
        float4 w3c = w3p[mt * 16 + 4 * g + 2];
        float4 w3d = w3p[mt * 16 + 4 * g + 3];
        float h0 = fmaxf(acc2[m4][0] + b2v.x, 0.f);
        float h1v = fmaxf(acc2[m4][1] + b2v.y, 0.f);
        float h2v = fmaxf(acc2[m4][2] + b2v.z, 0.f);
        float h3 = fmaxf(acc2[m4][3] + b2v.w, 0.f);
        o0 += h0 * w3a.x + h1v * w3b.x + h2v * w3c.x + h3 * w3d.x;
        o1 += h0 * w3a.y + h1v * w3b.y + h2v * w3c.y + h3 * w3d.y;
        o2 += h0 * w3a.z + h1v * w3b.z + h2v * w3c.z + h3 * w3d.z;
        FENCE();   // <=5 float4 (20 VGPR) of epilogue loads in flight
      }
    }
    o0 += __shfl_xor(o0, 16); o0 += __shfl_xor(o0, 32);
    o1 += __shfl_xor(o1, 16); o1 += __shfl_xor(o1, 32);
    o2 += __shfl_xor(o2, 16); o2 += __shfl_xor(o2, 32);

    if (g == 0) {
      float* op = out + p * 3;
      op[0] = o0 + b3[0];
      op[1] = o1 + b3[1];
      op[2] = o2 + b3[2];
    }
  }
}

extern "C" void kernel_launch(void* const* d_in, const int* in_sizes, int n_in,
                              void* d_out, int out_size, void* d_ws, size_t ws_size,
                              hipStream_t stream) {
  const float* coords = (const float*)d_in[0];
  const float* grid_p = (const float*)d_in[1];
  const float* W1 = (const float*)d_in[2];
  const float* b1 = (const float*)d_in[3];
  const float* W2 = (const float*)d_in[4];
  const float* b2 = (const float*)d_in[5];
  const float* W3 = (const float*)d_in[6];
  const float* b3 = (const float*)d_in[7];
  float* out = (float*)d_out;

  bf16* w1f = (bf16*)((unsigned char*)d_ws + WS_W1F);
  bf16* w2f = (bf16*)((unsigned char*)d_ws + WS_W2F);
  float4* w3p = (float4*)((unsigned char*)d_ws + WS_W3P);

  int N = in_sizes[0] / 2;                    // coords is (N,2); N = 1<<20
  int iters = N / (NBLOCKS * PTS_PER_ITER);   // = 8

  nf_prep<<<321, 256, 0, stream>>>(W1, W2, W3, w1f, w2f, w3p);

  nf_fused<<<NBLOCKS, 512, 0, stream>>>(
      coords, grid_p, b1, b2, b3, (const bf16*)d_ws, w3p, out, iters);
}

// Round 9
// 495.307 us; speedup vs baseline: 1.5751x; 1.5751x over previous
//
#include <hip/hip_runtime.h>
#include <stdint.h>

typedef __bf16 bf16;
typedef bf16 bf16x8 __attribute__((ext_vector_type(8)));
typedef float f32x4 __attribute__((ext_vector_type(4)));

#define GRID_H 512
#define GRID_W 512
#define FD 64
#define HD 256

// ---- ws layout (bytes) ----
#define WS_W1F 0          // 32768  : W1 frags, 32 blocks of 1KB, id = kt*16+mt (kt<2)
#define WS_W2F 32768      // 131072 : W2 frags, 128 blocks, id = kt*16+mt (kt<8)  [pi-permuted k]
#define WS_W3P 163840     // 4096   : 256 x float4 (w3 row padded)

// ---- LDS layout (bytes): weights only, staged once per block ----
#define LDS_W1 0          // 32768
#define LDS_W2 32768      // 131072
#define LDS_TOTAL 163840  // 160 KiB static

#define NBLOCKS 1024
#define PTS_PER_ITER 128  // 4 waves x 32 pts

#define FENCE() __builtin_amdgcn_sched_barrier(0)

__device__ __forceinline__ f32x4 mfma16(bf16x8 a, bf16x8 b, f32x4 c) {
  return __builtin_amdgcn_mfma_f32_16x16x32_bf16(a, b, c, 0, 0, 0);
}

// Fragment convention (A and B operands, consistent on both sides):
//   position (lane, j) <-> k = 32*kt + 8*(lane>>4) + j ; m/n = 16*mt + (lane&15)
// W2 ONLY: k-space is pi-permuted so that L1's D-fragments ARE L2's B-fragments
// in-lane:  channel stored at B-position (kt,g,j) = 32*kt + 16*(j>>2) + 4*g + (j&3).
// (R4-verified correct.)
__global__ __launch_bounds__(256) void nf_prep(
    const float* __restrict__ W1, const float* __restrict__ W2,
    const float* __restrict__ W3,
    bf16* __restrict__ w1f, bf16* __restrict__ w2f, float4* __restrict__ w3p)
{
  int t = blockIdx.x * 256 + threadIdx.x;
  if (t < 16384) {                       // W1^T frags: A[m=out][k=in] = W1[k][m]
    int e = t, blk = e >> 9, el = e & 511;
    int lane = el >> 3, j = el & 7;
    int kt = blk >> 4, mt = blk & 15;
    int k = kt * 32 + (lane >> 4) * 8 + j;   // in-ch < 64 (standard convention)
    int m = mt * 16 + (lane & 15);           // out-ch < 256
    w1f[e] = (bf16)W1[k * HD + m];
  } else if (t < 16384 + 65536) {        // W2^T frags with pi-permuted k
    int e = t - 16384, blk = e >> 9, el = e & 511;
    int lane = el >> 3, j = el & 7;
    int kt = blk >> 4, mt = blk & 15;
    int k = kt * 32 + ((j >> 2) << 4) + ((lane >> 4) << 2) + (j & 3);  // pi(k_pos)
    int m = mt * 16 + (lane & 15);           // out-ch < 256
    w2f[e] = (bf16)W2[k * HD + m];
  } else if (t < 16384 + 65536 + 256) {  // W3 rows padded to float4
    int c = t - 16384 - 65536;
    w3p[c] = make_float4(W3[c * 3 + 0], W3[c * 3 + 1], W3[c * 3 + 2], 0.f);
  }
}

// Persistent fused kernel: 1024 blocks x 256 threads (4 waves), 8 iters of
// 128 points (32 pts/wave as TWO 16-pt n-tiles sharing every A-frag read).
// vs R8: 256-thread blocks.  Empirical finding R4-R8: 8-wave workgroups get a
// hard 128-VGPR budget (4 waves/EU heuristic; LDS/attrs ignored) -> h1b
// spilled -> ~2 GB scratch = whole runtime.  4-wave WG + static 160 KB LDS
// -> 1 WG/CU -> 1 wave/EU -> 256+ VGPR budget: h1b x2 (64) + acc (32) + bfr
// (16) fit with slack.  Widening to 32 pts/wave also HALVES per-point LDS
// weight traffic (the structural floor): ~10 -> ~5 KB/pt.
__global__ __launch_bounds__(256) void nf_fused(
    const float* __restrict__ coords, const float* __restrict__ grid,
    const float* __restrict__ b1, const float* __restrict__ b2,
    const float* __restrict__ b3,
    const bf16* __restrict__ wsf, const float4* __restrict__ w3p,
    float* __restrict__ out, int iters)
{
  __shared__ __align__(16) unsigned char lds[LDS_TOTAL];   // static 160 KiB
  const int tid = threadIdx.x;
  const int w = tid >> 6;        // wave id (0..3): owns 32 points per iter
  const int l = tid & 63;
  const int g = l >> 4;          // lane group
  const int r15 = l & 15;

  // ---------- stage W1f+W2f (contiguous 160 KB in ws) into LDS, once ----------
  {
    const uint4* src = (const uint4*)wsf;
    uint4* dst = (uint4*)lds;
#pragma unroll 4
    for (int i = 0; i < 40; ++i) dst[i * 256 + tid] = src[i * 256 + tid];
  }
  __syncthreads();   // the only barrier in the kernel

  const unsigned char* ldsA = lds + (unsigned)(l * 16);

  for (int it = 0; it < iters; ++it) {
    const int pbase = blockIdx.x * (iters * PTS_PER_ITER) + it * PTS_PER_ITER +
                      w * 32 + r15;

    // ---------- bilinear gather -> feats B-frags, two 16-pt tiles ----------
    // B-frag (lane l, j) <-> k(ch) = kt*32 + 8g + j ; n(pt) = pt*16 + r15
    bf16x8 bfr[2][2];   // [pt][kt]
#pragma unroll
    for (int pt = 0; pt < 2; ++pt) {
      const int p = pbase + pt * 16;
      float2 cxy = *(const float2*)(coords + 2 * p);
      float px = (cxy.x * 0.5f + 0.5f) * (float)(GRID_W - 1);
      float py = (cxy.y * 0.5f + 0.5f) * (float)(GRID_H - 1);
      float fx = fminf(fmaxf(floorf(px), 0.f), (float)(GRID_W - 2));
      float fy = fminf(fmaxf(floorf(py), 0.f), (float)(GRID_H - 2));
      int x0 = (int)fx, y0 = (int)fy;
      float tx = px - fx, ty = py - fy;
      float w00 = (1.f - tx) * (1.f - ty);
      float w01 = tx * (1.f - ty);
      float w10 = (1.f - tx) * ty;
      float w11 = tx * ty;
      const float4* p00 = (const float4*)grid + (y0 * GRID_W + x0) * (FD / 4);
      const float4* p01 = p00 + (FD / 4);
      const float4* p10 = p00 + GRID_W * (FD / 4);
      const float4* p11 = p10 + (FD / 4);
#pragma unroll
      for (int kt = 0; kt < 2; ++kt) {
#pragma unroll
        for (int q = 0; q < 2; ++q) {
          int idx = kt * 8 + 2 * g + q;   // float4 index: ch = 4*idx
          float4 a = p00[idx], b = p01[idx], c = p10[idx], d = p11[idx];
          float f0 = a.x * w00 + b.x * w01 + c.x * w10 + d.x * w11;
          float f1 = a.y * w00 + b.y * w01 + c.y * w10 + d.y * w11;
          float f2 = a.z * w00 + b.z * w01 + c.z * w10 + d.z * w11;
          float f3 = a.w * w00 + b.w * w01 + c.w * w10 + d.w * w11;
          bfr[pt][kt][q * 4 + 0] = (bf16)f0;
          bfr[pt][kt][q * 4 + 1] = (bf16)f1;
          bfr[pt][kt][q * 4 + 2] = (bf16)f2;
          bfr[pt][kt][q * 4 + 3] = (bf16)f3;
        }
      }
      FENCE();   // <=16 float4 gather loads in flight per point-tile
    }

    // ---------- layer 1 + h1 epilogue, four m-quarters; af shared by 2 tiles --
    // D mapping: pt(col) = r15, ch(row) = mt*16 + 4g + reg.
    // pi-permuted W2 expects B-position (kt,g,j) = ch 32kt+16(j>>2)+4g+(j&3)
    //   -> h1b[pt][mt>>1][(mt&1)*4+reg] = D(mt, reg).  Zero cross-lane movement.
    bf16x8 h1b[2][8];
#pragma unroll
    for (int q4 = 0; q4 < 4; ++q4) {
      f32x4 acc1[2][4];
#pragma unroll
      for (int m4 = 0; m4 < 4; ++m4) {
        acc1[0][m4] = (f32x4){0.f, 0.f, 0.f, 0.f};
        acc1[1][m4] = (f32x4){0.f, 0.f, 0.f, 0.f};
      }
#pragma unroll
      for (int kt = 0; kt < 2; ++kt) {
#pragma unroll
        for (int m4 = 0; m4 < 4; ++m4) {
          bf16x8 af = *(const bf16x8*)(ldsA + LDS_W1 +
                                       (kt * 16 + q4 * 4 + m4) * 1024);
          acc1[0][m4] = mfma16(af, bfr[0][kt], acc1[0][m4]);
          acc1[1][m4] = mfma16(af, bfr[1][kt], acc1[1][m4]);
        }
        FENCE();   // <=4 af (32 VGPR) in flight per segment
      }
#pragma unroll
      for (int m4 = 0; m4 < 4; ++m4) {
        int mt = q4 * 4 + m4;
        float4 b1v = *(const float4*)(b1 + mt * 16 + 4 * g);
        int kt2 = mt >> 1, hh = mt & 1;
#pragma unroll
        for (int pt = 0; pt < 2; ++pt) {
          h1b[pt][kt2][hh * 4 + 0] = (bf16)fmaxf(acc1[pt][m4][0] + b1v.x, 0.f);
          h1b[pt][kt2][hh * 4 + 1] = (bf16)fmaxf(acc1[pt][m4][1] + b1v.y, 0.f);
          h1b[pt][kt2][hh * 4 + 2] = (bf16)fmaxf(acc1[pt][m4][2] + b1v.z, 0.f);
          h1b[pt][kt2][hh * 4 + 3] = (bf16)fmaxf(acc1[pt][m4][3] + b1v.w, 0.f);
        }
      }
      FENCE();   // quarter's h1 packed before next quarter's loads issue
    }

    // ---------- layer 2 + layer 3, four m-quarters; af shared by 2 tiles ----
    float o0a = 0.f, o1a = 0.f, o2a = 0.f;   // pt = 0
    float o0b = 0.f, o1b = 0.f, o2b = 0.f;   // pt = 1
#pragma unroll
    for (int q4 = 0; q4 < 4; ++q4) {
      f32x4 acc2[2][4];
#pragma unroll
      for (int m4 = 0; m4 < 4; ++m4) {
        acc2[0][m4] = (f32x4){0.f, 0.f, 0.f, 0.f};
        acc2[1][m4] = (f32x4){0.f, 0.f, 0.f, 0.f};
      }
#pragma unroll
      for (int kt = 0; kt < 8; ++kt) {
#pragma unroll
        for (int m4 = 0; m4 < 4; ++m4) {
          bf16x8 af = *(const bf16x8*)(ldsA + LDS_W2 +
                                       (kt * 16 + q4 * 4 + m4) * 1024);
          acc2[0][m4] = mfma16(af, h1b[0][kt], acc2[0][m4]);
          acc2[1][m4] = mfma16(af, h1b[1][kt], acc2[1][m4]);
        }
        FENCE();   // <=4 af (32 VGPR) in flight per kt segment
      }
      // L3 partials for this quarter (fp32, registers); W3/b2 shared by tiles
#pragma unroll
      for (int m4 = 0; m4 < 4; ++m4) {
        int mt = q4 * 4 + m4;
        float4 b2v = *(const float4*)(b2 + mt * 16 + 4 * g);
        float4 w3a = w3p[mt * 16 + 4 * g + 0];
        float4 w3b = w3p[mt * 16 + 4 * g + 1];
        float4 w3c = w3p[mt * 16 + 4 * g + 2];
        float4 w3d = w3p[mt * 16 + 4 * g + 3];
        {
          float h0 = fmaxf(acc2[0][m4][0] + b2v.x, 0.f);
          float h1v = fmaxf(acc2[0][m4][1] + b2v.y, 0.f);
          float h2v = fmaxf(acc2[0][m4][2] + b2v.z, 0.f);
          float h3 = fmaxf(acc2[0][m4][3] + b2v.w, 0.f);
          o0a += h0 * w3a.x + h1v * w3b.x + h2v * w3c.x + h3 * w3d.x;
          o1a += h0 * w3a.y + h1v * w3b.y + h2v * w3c.y + h3 * w3d.y;
          o2a += h0 * w3a.z + h1v * w3b.z + h2v * w3c.z + h3 * w3d.z;
        }
        {
          float h0 = fmaxf(acc2[1][m4][0] + b2v.x, 0.f);
          float h1v = fmaxf(acc2[1][m4][1] + b2v.y, 0.f);
          float h2v = fmaxf(acc2[1][m4][2] + b2v.z, 0.f);
          float h3 = fmaxf(acc2[1][m4][3] + b2v.w, 0.f);
          o0b += h0 * w3a.x + h1v * w3b.x + h2v * w3c.x + h3 * w3d.x;
          o1b += h0 * w3a.y + h1v * w3b.y + h2v * w3c.y + h3 * w3d.y;
          o2b += h0 * w3a.z + h1v * w3b.z + h2v * w3c.z + h3 * w3d.z;
        }
      }
      FENCE();   // epilogue loads bounded per quarter
    }
    o0a += __shfl_xor(o0a, 16); o0a += __shfl_xor(o0a, 32);
    o1a += __shfl_xor(o1a, 16); o1a += __shfl_xor(o1a, 32);
    o2a += __shfl_xor(o2a, 16); o2a += __shfl_xor(o2a, 32);
    o0b += __shfl_xor(o0b, 16); o0b += __shfl_xor(o0b, 32);
    o1b += __shfl_xor(o1b, 16); o1b += __shfl_xor(o1b, 32);
    o2b += __shfl_xor(o2b, 16); o2b += __shfl_xor(o2b, 32);

    if (g == 0) {
      float* opa = out + (pbase) * 3;
      opa[0] = o0a + b3[0];
      opa[1] = o1a + b3[1];
      opa[2] = o2a + b3[2];
      float* opb = out + (pbase + 16) * 3;
      opb[0] = o0b + b3[0];
      opb[1] = o1b + b3[1];
      opb[2] = o2b + b3[2];
    }
  }
}

extern "C" void kernel_launch(void* const* d_in, const int* in_sizes, int n_in,
                              void* d_out, int out_size, void* d_ws, size_t ws_size,
                              hipStream_t stream) {
  const float* coords = (const float*)d_in[0];
  const float* grid_p = (const float*)d_in[1];
  const float* W1 = (const float*)d_in[2];
  const float* b1 = (const float*)d_in[3];
  const float* W2 = (const float*)d_in[4];
  const float* b2 = (const float*)d_in[5];
  const float* W3 = (const float*)d_in[6];
  const float* b3 = (const float*)d_in[7];
  float* out = (float*)d_out;

  bf16* w1f = (bf16*)((unsigned char*)d_ws + WS_W1F);
  bf16* w2f = (bf16*)((unsigned char*)d_ws + WS_W2F);
  float4* w3p = (float4*)((unsigned char*)d_ws + WS_W3P);

  int N = in_sizes[0] / 2;                    // coords is (N,2); N = 1<<20
  int iters = N / (NBLOCKS * PTS_PER_ITER);   // = 8

  nf_prep<<<321, 256, 0, stream>>>(W1, W2, W3, w1f, w2f, w3p);

  nf_fused<<<NBLOCKS, 256, 0, stream>>>(
      coords, grid_p, b1, b2, b3, (const bf16*)d_ws, w3p, out, iters);
}